// Round 7
// baseline (2862.179 us; speedup 1.0000x reference)
//
#include <hip/hip_runtime.h>

#define TS 100
#define NB 1024
#define NF 784
#define NH 200
#define NO 10
#define TT 20             // timesteps (combos) per group, per thread
#define NG (TS / TT)      // 5 groups
#define KSUB 28           // k-slice per pass (floats)
#define NP (NF / KSUB)    // 28 passes
#define KQ (KSUB / 4)     // 7 float4 per row-slice

// Block = 256 threads = 4 waves, owns ONE batch row b = blockIdx.x (grid 1024
// -> 4 blocks/CU, 16 waves/CU). Per group of 20 timesteps:
//   for each of 28 k-passes: stage W0[:,kslice] tile (22.4 KB) in LDS,
//   GEMM: thread h=tid (<200) reads its w4 from LDS (1 ds_read_b128 per kq)
//   and x4 via WAVE-UNIFORM global loads (scalarizes; no LDS pipe) ->
//   acc[20] k-ascending fmaf chains. Then 20 in-register LIF steps, spikes
//   stay in registers; wave-parallel Wout butterfly partials -> LDS ->
//   wave 0 runs the serial LI chain and writes out.
//
// NUMERICS CONTRACT (bitwise-matches the round-5 kernel that passed @1.95e-3):
//  - z chain: acc=0; fmaf over k=0..783 strictly ascending (x,y,z,w within
//    each float4); z = acc + bias as a trailing add
//  - LIF: vd = fmaf(0.1f, cu-v, v); spk = vd>1; v=(1-spk)*vd; cu=fmaf(0.8f,cu,z)
//  - LI:  vn = fmaf(0.1f, ili-vli, vli); ili = fmaf(0.8f, ili, s)
//  The Wout-reduce order MAY differ from round 5 (feeds only the linear LI
//  layer, no threshold downstream). Do NOT reorder the z/LIF chains.
__global__ __launch_bounds__(256) void fused_kernel(
    const float* __restrict__ x, const float* __restrict__ W0,
    const float* __restrict__ b0, const float* __restrict__ Wout,
    float* __restrict__ out)
{
    __shared__ float wt[NH * KSUB];        // 22.4 KB W0 k-slice tile
    __shared__ float psPart[4][TT][NO];    // 3.2 KB per-wave partial sums

    const int tid  = threadIdx.x;
    const int lane = tid & 63;
    const int wv   = tid >> 6;
    const int b    = blockIdx.x;
    const bool hval = (tid < NH);

    const float bias_h = hval ? b0[tid] : 0.f;
    float wo[NO];
    #pragma unroll
    for (int o = 0; o < NO; ++o)
        wo[o] = hval ? Wout[o * NH + tid] : 0.f;

    float v = 0.f, cu = 0.f;        // LIF state for h = tid
    float vli = 0.f, ili = 0.f;     // LI state (used by wave 0 only)

    for (int g = 0; g < NG; ++g) {
        float acc[TT];
        #pragma unroll
        for (int c = 0; c < TT; ++c) acc[c] = 0.f;

        for (int p = 0; p < NP; ++p) {
            __syncthreads();   // protect wt from previous pass's readers
            // ---- stage W0[:, p*28 .. p*28+28) -> wt[200][28], float4 ----
            for (int f = tid; f < NH * KQ; f += 256) {
                const int h = f / KQ;
                const int j = f - h * KQ;
                *(float4*)&wt[h * KSUB + 4 * j] =
                    *(const float4*)&W0[(size_t)h * NF + p * KSUB + 4 * j];
            }
            __syncthreads();

            // ---- GEMM slice: 1 LDS b128 per kq, x via uniform global loads
            if (hval) {
                const float* xb = x + ((size_t)(g * TT) * NB + b) * NF + p * KSUB;
                #pragma unroll
                for (int j = 0; j < KQ; ++j) {
                    const float4 w4 = *(const float4*)&wt[tid * KSUB + 4 * j];
                    #pragma unroll
                    for (int c = 0; c < TT; ++c) {
                        const float4 x4 =
                            *(const float4*)&xb[(size_t)c * NB * NF + 4 * j];
                        float a = acc[c];
                        a = fmaf(w4.x, x4.x, a);
                        a = fmaf(w4.y, x4.y, a);
                        a = fmaf(w4.z, x4.z, a);
                        a = fmaf(w4.w, x4.w, a);
                        acc[c] = a;
                    }
                }
            }
        }

        // ---- 20 LIF steps in registers (t ascending; spikes stay in regs) --
        float spk[TT];
        #pragma unroll
        for (int c = 0; c < TT; ++c) spk[c] = 0.f;
        if (hval) {
            #pragma unroll
            for (int c = 0; c < TT; ++c) {
                const float z  = acc[c] + bias_h;              // fl(acc+b)
                const float vd = fmaf(0.1f, cu - v, v);
                const float s  = vd > 1.0f ? 1.0f : 0.0f;
                v  = (1.0f - s) * vd;
                cu = fmaf(0.8f, cu, z);
                spk[c] = s;
            }
        }

        // ---- Phase A: per-wave butterfly partials of spk @ Wout.T ----
        for (int c = 0; c < TT; ++c) {
            float pr[NO];
            #pragma unroll
            for (int o = 0; o < NO; ++o) pr[o] = spk[c] * wo[o];
            #pragma unroll
            for (int m = 1; m < 64; m <<= 1)
                #pragma unroll
                for (int o = 0; o < NO; ++o)
                    pr[o] += __shfl_xor(pr[o], m, 64);
            float ps = pr[0];
            #pragma unroll
            for (int o = 1; o < NO; ++o) ps = (lane == o) ? pr[o] : ps;
            if (lane < NO) psPart[wv][c][lane] = ps;
        }
        __syncthreads();

        // ---- Phase B: wave 0 runs the serial LI chain ----
        if (wv == 0) {
            #pragma unroll
            for (int c = 0; c < TT; ++c) {
                float s = 0.f;
                if (lane < NO)
                    s = ((psPart[0][c][lane] + psPart[1][c][lane])
                         + psPart[2][c][lane]) + psPart[3][c][lane];
                const float vn = fmaf(0.1f, ili - vli, vli);   // OLD i_li
                ili = fmaf(0.8f, ili, s);
                vli = vn;
                if (lane < NO)
                    out[((size_t)(g * TT + c) * NB + b) * NO + lane] = vn;
            }
        }
        // next group's first pass barrier orders Phase B before wt re-stage;
        // psPart is rewritten only after that barrier chain -> no hazard.
    }
}

extern "C" void kernel_launch(void* const* d_in, const int* in_sizes, int n_in,
                              void* d_out, int out_size, void* d_ws, size_t ws_size,
                              hipStream_t stream)
{
    const float* x  = (const float*)d_in[0];   // [100,1024,784]
    const float* W0 = (const float*)d_in[1];   // [200,784]
    const float* b0 = (const float*)d_in[2];   // [200]
    const float* Wo = (const float*)d_in[3];   // [10,200]
    float* out = (float*)d_out;                // [100,1024,10] f32

    (void)d_ws; (void)ws_size; (void)in_sizes; (void)n_in; (void)out_size;
    fused_kernel<<<NB, 256, 0, stream>>>(x, W0, b0, Wo, out);
}

// Round 8
// 1095.650 us; speedup vs baseline: 2.6123x; 2.6123x over previous
//
#include <hip/hip_runtime.h>

#define TS 100
#define NB 1024
#define NF 784
#define NH 200
#define NO 10
#define BT 2              // batch rows per block
#define TT 50             // timesteps per group
#define NG (TS / TT)      // 2 groups
#define MT (BT * TT)      // 100 M-rows per group (row = 2*t + b)
#define KS 56             // k per slice
#define NSL (NF / KS)     // 14 slices
#define KQN (KS / 4)      // 14 float4 per slice-row
#define RSZ 16            // padded row size in float4 (64 floats, swizzle room)
#define CI 10             // row-combos per thread
#define HJ 8              // h per thread
#define ZLD 208           // zbuf/spk row stride (floats)

// Grid 512 (=2 blocks/CU), block 256 = 4 waves. Block owns BT=2 batch rows.
// Thread tid = j*10 + i (j in [0,25): h-octet 8j..8j+8; i in [0,10): rows
// 10c+i, c in [0,10)). Per group of 50 t: 14 k-slices staged in LDS (Xs
// 100x64f, Ws 200x64f, XOR-swizzled slots for conflict-free b128 reads),
// microtile GEMM accumulates acc[10][8]; then 5 chunks of 20 rows:
// z->LDS, LIF (thread=h, state in regs), spikes->LDS, per-wave butterfly
// reduce, wave-0 serial LI chain -> out. No workspace; writes only d_out.
//
// NUMERICS CONTRACT (bitwise-matches rounds 5/7 which passed @1.95e-3):
//  - z: acc=0; one thread owns (row,h) for ALL k=0..783, fmaf strictly
//    ascending (x,y,z,w within each float4); z = acc + bias trailing add
//  - LIF: vd=fmaf(0.1f,cu-v,v); spk=vd>1; v=(1-spk)*vd; cu=fmaf(0.8f,cu,z)
//  - LI:  vn=fmaf(0.1f,ili-vli,vli); ili=fmaf(0.8f,ili,s)
// Spike threshold is a cliff — do NOT reorder the z/LIF chains.
__global__ __launch_bounds__(256, 2) void fused_kernel(
    const float* __restrict__ x, const float* __restrict__ W0,
    const float* __restrict__ b0, const float* __restrict__ Wout,
    float* __restrict__ out)
{
    __shared__ __align__(16) float4 smem[(MT + NH) * RSZ];  // 76.8 KB
    float4* XsF4 = smem;                 // [100*16] f4
    float4* WsF4 = smem + MT * RSZ;      // [200*16] f4
    // overlay (used only between barriers, after GEMM phase)
    float* zbuf = (float*)smem;                  // [20][ZLD]
    float* spkb = zbuf + 20 * ZLD;               // [20][ZLD]
    float* psum = spkb + 20 * ZLD;               // [20][16]

    const int tid  = threadIdx.x;
    const int lane = tid & 63;
    const int wv   = tid >> 6;
    const int j    = tid / 10;          // h-octet index (valid < 25)
    const int i    = tid - j * 10;      // row-phase
    const bool act = (tid < 250);
    const bool hok = (tid < NH);
    const int bBase = blockIdx.x * BT;

    const float bias_h = hok ? b0[tid] : 0.f;

    // Wout fragments for reduce phase: h = lane + 64*s
    float wo[4][NO];
    bool  hv[4];
    #pragma unroll
    for (int s = 0; s < 4; ++s) {
        const int h = lane + 64 * s;
        hv[s] = (h < NH);
        #pragma unroll
        for (int o = 0; o < NO; ++o)
            wo[s][o] = hv[s] ? Wout[o * NH + h] : 0.f;
    }

    float v[BT], cu[BT];                // LIF state, thread = h
    #pragma unroll
    for (int b = 0; b < BT; ++b) { v[b] = 0.f; cu[b] = 0.f; }
    float vli[BT], ili[BT];             // LI state (wave 0, lane<10)
    #pragma unroll
    for (int b = 0; b < BT; ++b) { vli[b] = 0.f; ili[b] = 0.f; }

    // per-c row constants (compile-time-indexed arrays)
    int rbase[CI], rsw[CI];
    #pragma unroll
    for (int c = 0; c < CI; ++c) {
        const int row = 10 * c + i;
        rbase[c] = row * RSZ;
        rsw[c]   = row & 7;
    }
    const int wbase = 8 * j * RSZ;
    const int wsw   = j & 7;

    for (int g = 0; g < NG; ++g) {
        float acc[CI][HJ];
        #pragma unroll
        for (int c = 0; c < CI; ++c)
            #pragma unroll
            for (int s = 0; s < HJ; ++s) acc[c][s] = 0.f;

        // ================= GEMM over 14 k-slices =================
        for (int p = 0; p < NSL; ++p) {
            __syncthreads();   // smem free of previous readers
            // stage Xs: 100 rows x 14 f4  (row = 2t+b)
            for (int f = tid; f < MT * KQN; f += 256) {
                const int row = f / KQN;
                const int kq  = f - row * KQN;
                const int t   = row >> 1, b = row & 1;
                XsF4[row * RSZ + (kq ^ (row & 7))] =
                    *(const float4*)&x[((size_t)(g * TT + t) * NB + bBase + b) * NF
                                       + p * KS + 4 * kq];
            }
            // stage Ws: 200 rows x 14 f4
            for (int f = tid; f < NH * KQN; f += 256) {
                const int h  = f / KQN;
                const int kq = f - h * KQN;
                WsF4[h * RSZ + (kq ^ ((h >> 3) & 7))] =
                    *(const float4*)&W0[(size_t)h * NF + p * KS + 4 * kq];
            }
            __syncthreads();

            if (act) {
                #pragma unroll 1
                for (int kq = 0; kq < KQN; ++kq) {
                    float4 w4[HJ];
                    #pragma unroll
                    for (int s = 0; s < HJ; ++s)
                        w4[s] = WsF4[wbase + s * RSZ + (kq ^ wsw)];
                    #pragma unroll
                    for (int c = 0; c < CI; ++c) {
                        const float4 x4 = XsF4[rbase[c] + (kq ^ rsw[c])];
                        #pragma unroll
                        for (int s = 0; s < HJ; ++s) {
                            float a = acc[c][s];
                            a = fmaf(w4[s].x, x4.x, a);
                            a = fmaf(w4[s].y, x4.y, a);
                            a = fmaf(w4[s].z, x4.z, a);
                            a = fmaf(w4[s].w, x4.w, a);
                            acc[c][s] = a;
                        }
                    }
                }
            }
        }

        // ======= 5 chunks of 20 rows: z -> LIF -> reduce -> LI =======
        for (int cc = 0; cc < 5; ++cc) {
            __syncthreads();   // smem overlay safe (GEMM done / prev chunk done)
            if (act) {
                #pragma unroll
                for (int q = 0; q < 2; ++q) {
                    const int cl = 2 * cc + q;
                    const int rl = 10 * q + i;          // row-in-chunk
                    float4 z0, z1;
                    z0.x = acc[cl][0]; z0.y = acc[cl][1];
                    z0.z = acc[cl][2]; z0.w = acc[cl][3];
                    z1.x = acc[cl][4]; z1.y = acc[cl][5];
                    z1.z = acc[cl][6]; z1.w = acc[cl][7];
                    *(float4*)&zbuf[rl * ZLD + 8 * j]     = z0;
                    *(float4*)&zbuf[rl * ZLD + 8 * j + 4] = z1;
                }
            }
            __syncthreads();
            // LIF: thread = h, 10 t x 2 b, t ascending (row = 2t+b)
            if (hok) {
                #pragma unroll
                for (int t2 = 0; t2 < 10; ++t2)
                    #pragma unroll
                    for (int b = 0; b < BT; ++b) {
                        const int rl = 2 * t2 + b;
                        const float z  = zbuf[rl * ZLD + tid] + bias_h;
                        const float vd = fmaf(0.1f, cu[b] - v[b], v[b]);
                        const float s  = vd > 1.0f ? 1.0f : 0.0f;
                        v[b]  = (1.0f - s) * vd;
                        cu[b] = fmaf(0.8f, cu[b], z);
                        spkb[rl * ZLD + tid] = s;
                    }
            }
            __syncthreads();
            // reduce: wave wv handles rows 5wv..5wv+5
            #pragma unroll
            for (int rr = 0; rr < 5; ++rr) {
                const int rl = 5 * wv + rr;
                float pr[NO];
                #pragma unroll
                for (int o = 0; o < NO; ++o) pr[o] = 0.f;
                #pragma unroll
                for (int s4 = 0; s4 < 4; ++s4) {
                    if (hv[s4]) {
                        const float sv = spkb[rl * ZLD + lane + 64 * s4];
                        #pragma unroll
                        for (int o = 0; o < NO; ++o)
                            pr[o] = fmaf(sv, wo[s4][o], pr[o]);
                    }
                }
                #pragma unroll
                for (int m = 1; m < 64; m <<= 1)
                    #pragma unroll
                    for (int o = 0; o < NO; ++o)
                        pr[o] += __shfl_xor(pr[o], m, 64);
                float ps = pr[0];
                #pragma unroll
                for (int o = 1; o < NO; ++o) ps = (lane == o) ? pr[o] : ps;
                if (lane < NO) psum[rl * 16 + lane] = ps;
            }
            __syncthreads();
            // LI: wave 0, serial over t then b (states per b)
            if (wv == 0) {
                #pragma unroll
                for (int t2 = 0; t2 < 10; ++t2)
                    #pragma unroll
                    for (int b = 0; b < BT; ++b) {
                        const int rl = 2 * t2 + b;
                        const float s = (lane < NO) ? psum[rl * 16 + lane] : 0.f;
                        const float vn = fmaf(0.1f, ili[b] - vli[b], vli[b]);
                        ili[b] = fmaf(0.8f, ili[b], s);
                        vli[b] = vn;
                        if (lane < NO)
                            out[((size_t)(g * TT + 10 * cc + t2) * NB
                                 + bBase + b) * NO + lane] = vn;
                    }
            }
        }
    }
}

extern "C" void kernel_launch(void* const* d_in, const int* in_sizes, int n_in,
                              void* d_out, int out_size, void* d_ws, size_t ws_size,
                              hipStream_t stream)
{
    const float* x  = (const float*)d_in[0];   // [100,1024,784]
    const float* W0 = (const float*)d_in[1];   // [200,784]
    const float* b0 = (const float*)d_in[2];   // [200]
    const float* Wo = (const float*)d_in[3];   // [10,200]
    float* out = (float*)d_out;                // [100,1024,10] f32

    (void)d_ws; (void)ws_size; (void)in_sizes; (void)n_in; (void)out_size;
    fused_kernel<<<NB / BT, 256, 0, stream>>>(x, W0, b0, Wo, out);
}